// Round 1
// baseline (693.761 us; speedup 1.0000x reference)
//
#include <hip/hip_runtime.h>
#include <math.h>

#define HDIM 256

// ---------------- CSR build ----------------

__global__ __launch_bounds__(256)
void deg_count_kernel(const int* __restrict__ ei, int* __restrict__ deg, int E) {
  int e = blockIdx.x * 256 + threadIdx.x;
  if (e < E) atomicAdd(&deg[ei[E + e]], 1);
}

__global__ __launch_bounds__(256)
void dinv_kernel(const int* __restrict__ deg, float* __restrict__ dinv, int n) {
  int i = blockIdx.x * 256 + threadIdx.x;
  if (i < n) dinv[i] = 1.0f / sqrtf((float)deg[i] + 1.0f);
}

__global__ __launch_bounds__(256)
void block_sum_kernel(const int* __restrict__ deg, int* __restrict__ bsum, int n) {
  __shared__ int sm[256];
  int t = threadIdx.x;
  int idx = blockIdx.x * 256 + t;
  sm[t] = (idx < n) ? deg[idx] : 0;
  __syncthreads();
  for (int off = 128; off > 0; off >>= 1) {
    if (t < off) sm[t] += sm[t + off];
    __syncthreads();
  }
  if (t == 0) bsum[blockIdx.x] = sm[0];
}

// nb <= 256 (N=50000 -> nb=196)
__global__ __launch_bounds__(256)
void scan_bsums_kernel(const int* __restrict__ bsum, int* __restrict__ boff,
                       int* __restrict__ rowptr, int nb, int n) {
  __shared__ int sm[256];
  int t = threadIdx.x;
  int v = (t < nb) ? bsum[t] : 0;
  sm[t] = v;
  __syncthreads();
  for (int off = 1; off < 256; off <<= 1) {
    int a = (t >= off) ? sm[t - off] : 0;
    __syncthreads();
    sm[t] += a;
    __syncthreads();
  }
  if (t < nb) boff[t] = sm[t] - v;   // exclusive block offset
  if (t == 255) rowptr[n] = sm[255]; // total == E
}

__global__ __launch_bounds__(256)
void scan_final_kernel(const int* __restrict__ deg, const int* __restrict__ boff,
                       int* __restrict__ rowptr, int* __restrict__ cursor, int n) {
  __shared__ int sm[256];
  int t = threadIdx.x;
  int idx = blockIdx.x * 256 + t;
  int v = (idx < n) ? deg[idx] : 0;
  sm[t] = v;
  __syncthreads();
  for (int off = 1; off < 256; off <<= 1) {
    int a = (t >= off) ? sm[t - off] : 0;
    __syncthreads();
    sm[t] += a;
    __syncthreads();
  }
  int excl = sm[t] - v + boff[blockIdx.x];
  if (idx < n) { rowptr[idx] = excl; cursor[idx] = excl; }
}

__global__ __launch_bounds__(256)
void fill_csr_kernel(const int* __restrict__ ei, int* __restrict__ cursor,
                     int* __restrict__ col, int E) {
  int e = blockIdx.x * 256 + threadIdx.x;
  if (e < E) {
    int s = ei[e];
    int d = ei[E + e];
    int p = atomicAdd(&cursor[d], 1);
    col[p] = s;
  }
}

// ---------------- fp32 tiled GEMM: C[M,256] = A[M,K] @ B[K,256] (+bias)(+relu) ----------------
// BM=BN=128, BK=8, 256 threads, 8x8 accum per thread. FMA-bound by construction:
// per k-step per lane: 64 FMA vs 64B LDS read.

template<int K, bool BIAS, bool RELU>
__global__ __launch_bounds__(256)
void gemm_kernel(const float* __restrict__ A, const float* __restrict__ B,
                 const float* __restrict__ bias, float* __restrict__ C, int M) {
  constexpr int BM = 128, BN = 128, BK = 8;
  __shared__ __align__(16) float As[BK][BM];  // transposed: As[k][m]
  __shared__ __align__(16) float Bs[BK][BN];
  const int tid = threadIdx.x;
  const int bm = blockIdx.y * BM;
  const int bn = blockIdx.x * BN;
  const int tx = tid & 15;
  const int ty = tid >> 4;

  float acc[8][8];
#pragma unroll
  for (int i = 0; i < 8; i++)
#pragma unroll
    for (int j = 0; j < 8; j++) acc[i][j] = 0.f;

  // A tile 128x8 = 256 threads x float4 ; B tile 8x128 = 256 threads x float4
  const int arow = tid >> 1;
  const int acol = (tid & 1) << 2;
  const int brow = tid >> 5;
  const int bcol = (tid & 31) << 2;
  const float* Ap = A + (size_t)(bm + arow) * K + acol;
  const float* Bp = B + (size_t)brow * HDIM + bn + bcol;
  const bool aok = (bm + arow) < M;

  for (int k0 = 0; k0 < K; k0 += BK) {
    float4 av = aok ? *(const float4*)Ap : make_float4(0.f, 0.f, 0.f, 0.f);
    float4 bv = *(const float4*)Bp;
    Ap += BK;
    Bp += (size_t)BK * HDIM;
    __syncthreads();
    As[acol + 0][arow] = av.x;
    As[acol + 1][arow] = av.y;
    As[acol + 2][arow] = av.z;
    As[acol + 3][arow] = av.w;
    *(float4*)&Bs[brow][bcol] = bv;
    __syncthreads();
#pragma unroll
    for (int kk = 0; kk < BK; ++kk) {
      float4 a0 = *(const float4*)&As[kk][ty * 8];
      float4 a1 = *(const float4*)&As[kk][ty * 8 + 4];
      float4 b0 = *(const float4*)&Bs[kk][tx * 8];
      float4 b1 = *(const float4*)&Bs[kk][tx * 8 + 4];
      float a[8] = {a0.x, a0.y, a0.z, a0.w, a1.x, a1.y, a1.z, a1.w};
      float b[8] = {b0.x, b0.y, b0.z, b0.w, b1.x, b1.y, b1.z, b1.w};
#pragma unroll
      for (int i = 0; i < 8; i++)
#pragma unroll
        for (int j = 0; j < 8; j++) acc[i][j] = fmaf(a[i], b[j], acc[i][j]);
    }
  }

  float bj[8];
#pragma unroll
  for (int j = 0; j < 8; j++) bj[j] = BIAS ? bias[bn + tx * 8 + j] : 0.f;
#pragma unroll
  for (int i = 0; i < 8; i++) {
    int row = bm + ty * 8 + i;
    if (row < M) {
      float4 v0, v1;
      v0.x = acc[i][0] + bj[0]; v0.y = acc[i][1] + bj[1];
      v0.z = acc[i][2] + bj[2]; v0.w = acc[i][3] + bj[3];
      v1.x = acc[i][4] + bj[4]; v1.y = acc[i][5] + bj[5];
      v1.z = acc[i][6] + bj[6]; v1.w = acc[i][7] + bj[7];
      if (RELU) {
        v0.x = fmaxf(v0.x, 0.f); v0.y = fmaxf(v0.y, 0.f);
        v0.z = fmaxf(v0.z, 0.f); v0.w = fmaxf(v0.w, 0.f);
        v1.x = fmaxf(v1.x, 0.f); v1.y = fmaxf(v1.y, 0.f);
        v1.z = fmaxf(v1.z, 0.f); v1.w = fmaxf(v1.w, 0.f);
      }
      float* Cp = C + (size_t)row * HDIM + bn + tx * 8;
      *(float4*)Cp = v0;
      *((float4*)Cp + 1) = v1;
    }
  }
}

// ---------------- GCN aggregation (pull via CSR), one wave per node ----------------
// out[i] = relu( dinv[i]^2 * t[i] + dinv[i] * sum_{e: dst=i} dinv[src_e] * t[src_e] + bias )

__global__ __launch_bounds__(256)
void aggregate_kernel(const float* __restrict__ t, const float* __restrict__ dinv,
                      const int* __restrict__ rowptr, const int* __restrict__ col,
                      const float* __restrict__ bias, float* __restrict__ outp, int n) {
  int gw = (int)((blockIdx.x * 256 + threadIdx.x) >> 6);  // node = global wave id
  int lane = threadIdx.x & 63;
  if (gw >= n) return;
  float di = dinv[gw];
  const float4* ti = (const float4*)(t + (size_t)gw * HDIM);
  float4 v = ti[lane];
  float ss = di * di;
  float ax = v.x * ss, ay = v.y * ss, az = v.z * ss, aw = v.w * ss;
  int e0 = rowptr[gw], e1 = rowptr[gw + 1];
  for (int e = e0; e < e1; ++e) {
    int s = col[e];
    float wgt = dinv[s] * di;
    const float4* ts = (const float4*)(t + (size_t)s * HDIM);
    float4 u = ts[lane];
    ax = fmaf(u.x, wgt, ax);
    ay = fmaf(u.y, wgt, ay);
    az = fmaf(u.z, wgt, az);
    aw = fmaf(u.w, wgt, aw);
  }
  const float4* b4 = (const float4*)bias;
  float4 bb = b4[lane];
  float4 r;
  r.x = fmaxf(ax + bb.x, 0.f);
  r.y = fmaxf(ay + bb.y, 0.f);
  r.z = fmaxf(az + bb.z, 0.f);
  r.w = fmaxf(aw + bb.w, 0.f);
  ((float4*)(outp + (size_t)gw * HDIM))[lane] = r;
}

// ---------------- row softmax, one wave per row (256 cols = 64 lanes x float4) ----------------

__global__ __launch_bounds__(256)
void softmax_kernel(const float* __restrict__ logits, float* __restrict__ outp, int n) {
  int gw = (int)((blockIdx.x * 256 + threadIdx.x) >> 6);
  int lane = threadIdx.x & 63;
  if (gw >= n) return;
  const float4* rp = (const float4*)(logits + (size_t)gw * HDIM);
  float4 v = rp[lane];
  float m = fmaxf(fmaxf(v.x, v.y), fmaxf(v.z, v.w));
#pragma unroll
  for (int off = 1; off < 64; off <<= 1) m = fmaxf(m, __shfl_xor(m, off));
  float ex = expf(v.x - m), ey = expf(v.y - m), ez = expf(v.z - m), ew = expf(v.w - m);
  float s = ex + ey + ez + ew;
#pragma unroll
  for (int off = 1; off < 64; off <<= 1) s += __shfl_xor(s, off);
  float inv = 1.0f / s;
  float4 r = make_float4(ex * inv, ey * inv, ez * inv, ew * inv);
  ((float4*)(outp + (size_t)gw * HDIM))[lane] = r;
}

// ---------------- launch ----------------

extern "C" void kernel_launch(void* const* d_in, const int* in_sizes, int n_in,
                              void* d_out, int out_size, void* d_ws, size_t ws_size,
                              hipStream_t stream) {
  const float* x   = (const float*)d_in[0];
  const int*   ei  = (const int*)d_in[1];
  const float* W1  = (const float*)d_in[2];
  const float* b1  = (const float*)d_in[3];
  const float* Wg1 = (const float*)d_in[4];
  const float* bg1 = (const float*)d_in[5];
  const float* Wg2 = (const float*)d_in[6];
  const float* bg2 = (const float*)d_in[7];
  const float* W2  = (const float*)d_in[8];
  const float* b2  = (const float*)d_in[9];
  const float* W3  = (const float*)d_in[10];
  const float* b3  = (const float*)d_in[11];
  float* out = (float*)d_out;

  const int K1 = in_sizes[2] / HDIM;  // 128
  const int N  = in_sizes[0] / K1;    // 50000
  const int E  = in_sizes[1] / 2;     // 300000

  // workspace layout (256B aligned chunks)
  char* w = (char*)d_ws;
  auto alloc = [&](size_t bytes) -> char* {
    char* p = w;
    w += (bytes + 255) & ~(size_t)255;
    return p;
  };
  float* bufA   = (float*)alloc((size_t)N * HDIM * sizeof(float));
  float* dinv   = (float*)alloc((size_t)N * sizeof(float));
  int*   deg    = (int*)alloc((size_t)N * sizeof(int));
  int*   rowptr = (int*)alloc((size_t)(N + 1) * sizeof(int));
  int*   cursor = (int*)alloc((size_t)N * sizeof(int));
  int*   col    = (int*)alloc((size_t)E * sizeof(int));
  const int nb  = (N + 255) / 256;
  int*   bsum   = (int*)alloc((size_t)nb * sizeof(int));
  int*   boff   = (int*)alloc((size_t)nb * sizeof(int));

  const int ge = (E + 255) / 256;
  const int gn = (N + 255) / 256;

  // CSR build (dst-sorted incoming edges) + dinv
  hipMemsetAsync(deg, 0, (size_t)N * sizeof(int), stream);
  deg_count_kernel<<<ge, 256, 0, stream>>>(ei, deg, E);
  dinv_kernel<<<gn, 256, 0, stream>>>(deg, dinv, N);
  block_sum_kernel<<<nb, 256, 0, stream>>>(deg, bsum, N);
  scan_bsums_kernel<<<1, 256, 0, stream>>>(bsum, boff, rowptr, nb, N);
  scan_final_kernel<<<nb, 256, 0, stream>>>(deg, boff, rowptr, cursor, N);
  fill_csr_kernel<<<ge, 256, 0, stream>>>(ei, cursor, col, E);

  dim3 ggrid(HDIM / 128, (N + 127) / 128);
  const int gagg = (N + 3) / 4;  // one wave per node, 4 waves/block

  // h0 = relu(x@W1+b1) -> bufA
  gemm_kernel<128, true, true><<<ggrid, 256, 0, stream>>>(x, W1, b1, bufA, N);
  // t1 = h0@Wg1 -> out (scratch)
  gemm_kernel<256, false, false><<<ggrid, 256, 0, stream>>>(bufA, Wg1, nullptr, out, N);
  // h1 = relu(agg(t1)+bg1) -> bufA
  aggregate_kernel<<<gagg, 256, 0, stream>>>(out, dinv, rowptr, col, bg1, bufA, N);
  // t2 = h1@Wg2 -> out
  gemm_kernel<256, false, false><<<ggrid, 256, 0, stream>>>(bufA, Wg2, nullptr, out, N);
  // h2 = relu(agg(t2)+bg2) -> bufA
  aggregate_kernel<<<gagg, 256, 0, stream>>>(out, dinv, rowptr, col, bg2, bufA, N);
  // h3 = relu(h2@W2+b2) -> out
  gemm_kernel<256, true, true><<<ggrid, 256, 0, stream>>>(bufA, W2, b2, out, N);
  // logits = h3@W3+b3 -> bufA
  gemm_kernel<256, true, false><<<ggrid, 256, 0, stream>>>(out, W3, b3, bufA, N);
  // out = softmax(logits)
  softmax_kernel<<<gagg, 256, 0, stream>>>(bufA, out, N);
}

// Round 2
// 462.915 us; speedup vs baseline: 1.4987x; 1.4987x over previous
//
#include <hip/hip_runtime.h>
#include <math.h>

#define HDIM 256

typedef float floatx4 __attribute__((ext_vector_type(4)));
typedef __bf16 bf16x8 __attribute__((ext_vector_type(8)));
typedef unsigned short ushortx4 __attribute__((ext_vector_type(4)));

#define AS1C(p) ((const __attribute__((address_space(1))) void*)(p))
#define AS3(p)  ((__attribute__((address_space(3))) void*)(p))

__device__ inline unsigned short bf16_rn(float f) {
  unsigned u = __float_as_uint(f);
  return (unsigned short)((u + 0x7FFFu + ((u >> 16) & 1u)) >> 16);
}

__device__ inline void split_f32(float f, unsigned short& h, unsigned short& l) {
  unsigned short hb = bf16_rn(f);
  float hf = __uint_as_float(((unsigned)hb) << 16);
  h = hb;
  l = bf16_rn(f - hf);
}

// ---------------- weight prep: W[K][256] fp32 -> Wt_hi/Wt_lo [256][K] bf16 ----------------

__global__ __launch_bounds__(256)
void prep_w_kernel(const float* __restrict__ W, unsigned short* __restrict__ WH,
                   unsigned short* __restrict__ WL, int kshift) {
  int idx = blockIdx.x * 256 + threadIdx.x;
  int K = 1 << kshift;
  if (idx >= (K << 8)) return;
  int c = idx >> kshift;
  int k = idx & (K - 1);
  float f = W[(size_t)k * HDIM + c];
  unsigned short h, l;
  split_f32(f, h, l);
  WH[idx] = h;
  WL[idx] = l;
}

// ---------------- CSR build ----------------

__global__ __launch_bounds__(256)
void deg_count_kernel(const int* __restrict__ ei, int* __restrict__ deg, int E) {
  int e = blockIdx.x * 256 + threadIdx.x;
  if (e < E) atomicAdd(&deg[ei[E + e]], 1);
}

__global__ __launch_bounds__(256)
void dinv_kernel(const int* __restrict__ deg, float* __restrict__ dinv, int n) {
  int i = blockIdx.x * 256 + threadIdx.x;
  if (i < n) dinv[i] = 1.0f / sqrtf((float)deg[i] + 1.0f);
}

__global__ __launch_bounds__(256)
void block_sum_kernel(const int* __restrict__ deg, int* __restrict__ bsum, int n) {
  __shared__ int sm[256];
  int t = threadIdx.x;
  int idx = blockIdx.x * 256 + t;
  sm[t] = (idx < n) ? deg[idx] : 0;
  __syncthreads();
  for (int off = 128; off > 0; off >>= 1) {
    if (t < off) sm[t] += sm[t + off];
    __syncthreads();
  }
  if (t == 0) bsum[blockIdx.x] = sm[0];
}

__global__ __launch_bounds__(256)
void scan_bsums_kernel(const int* __restrict__ bsum, int* __restrict__ boff,
                       int* __restrict__ rowptr, int nb, int n) {
  __shared__ int sm[256];
  int t = threadIdx.x;
  int v = (t < nb) ? bsum[t] : 0;
  sm[t] = v;
  __syncthreads();
  for (int off = 1; off < 256; off <<= 1) {
    int a = (t >= off) ? sm[t - off] : 0;
    __syncthreads();
    sm[t] += a;
    __syncthreads();
  }
  if (t < nb) boff[t] = sm[t] - v;
  if (t == 255) rowptr[n] = sm[255];
}

__global__ __launch_bounds__(256)
void scan_final_kernel(const int* __restrict__ deg, const int* __restrict__ boff,
                       int* __restrict__ rowptr, int* __restrict__ cursor, int n) {
  __shared__ int sm[256];
  int t = threadIdx.x;
  int idx = blockIdx.x * 256 + t;
  int v = (idx < n) ? deg[idx] : 0;
  sm[t] = v;
  __syncthreads();
  for (int off = 1; off < 256; off <<= 1) {
    int a = (t >= off) ? sm[t - off] : 0;
    __syncthreads();
    sm[t] += a;
    __syncthreads();
  }
  int excl = sm[t] - v + boff[blockIdx.x];
  if (idx < n) { rowptr[idx] = excl; cursor[idx] = excl; }
}

__global__ __launch_bounds__(256)
void fill_csr_kernel(const int* __restrict__ ei, int* __restrict__ cursor,
                     int* __restrict__ col, int E) {
  int e = blockIdx.x * 256 + threadIdx.x;
  if (e < E) {
    int s = ei[e];
    int d = ei[E + e];
    int p = atomicAdd(&cursor[d], 1);
    col[p] = s;
  }
}

// ---------------- bf16x3 split MFMA GEMM ----------------
// C[M,256] = A[M,K] @ W[K,256] (+bias)(+relu), A fp32 (split in-kernel),
// W pre-split into transposed hi/lo bf16 [256][K].
// Tile 128x128, BK=32, 4 waves x (64x64 via 4x4 frags of 16x16x32).
// A*B ~= Ah*Bh + Ah*Bl + Al*Bh  (fp32 accumulate).

template<bool BIAS, bool RELU>
__global__ __launch_bounds__(256, 3)
void mfma_gemm_kernel(const float* __restrict__ A,
                      const unsigned short* __restrict__ WH,
                      const unsigned short* __restrict__ WL,
                      const float* __restrict__ bias,
                      float* __restrict__ C, int M, int K) {
  // A tiles: padded row-major [128][40] (pad 32->40: 80B stride, <=2-way conflicts)
  __shared__ __align__(16) unsigned short AsH[128 * 40];
  __shared__ __align__(16) unsigned short AsL[128 * 40];
  // B tiles: chunk-major [kc(4)][col(128)] of 8-bf16 chunks -> conflict-free reads
  __shared__ __align__(16) unsigned short BsH[4096];
  __shared__ __align__(16) unsigned short BsL[4096];

  const int tid = threadIdx.x;
  const int w = tid >> 6;
  const int l = tid & 63;
  const int l15 = l & 15;
  const int quad = l >> 4;
  const int wm = w & 1;
  const int wn = w >> 1;
  const int bm = blockIdx.y * 128;
  const int bn = blockIdx.x * 128;

  floatx4 acc[4][4];
#pragma unroll
  for (int i = 0; i < 4; ++i)
#pragma unroll
    for (int j = 0; j < 4; ++j) acc[i][j] = (floatx4){0.f, 0.f, 0.f, 0.f};

  for (int k0 = 0; k0 < K; k0 += 32) {
    // --- A global loads into registers (coalesced float4) ---
    float4 av[4];
#pragma unroll
    for (int i = 0; i < 4; ++i) {
      int chunk = i * 256 + tid;      // 0..1023 over 128 rows x 8 float4
      int row = chunk >> 3;
      int kc4 = chunk & 7;
      int grow = bm + row;
      if (grow > M - 1) grow = M - 1;
      av[i] = *(const float4*)(A + (size_t)grow * K + k0 + kc4 * 4);
    }

    __syncthreads();  // prior tile's LDS reads complete

    // --- B tile via global_load_lds (16B/lane), chunk L = kc*128+col ---
#pragma unroll
    for (int j = 0; j < 2; ++j) {
      int L = j * 256 + w * 64 + l;   // 0..511
      int kc = L >> 7;
      int colL = L & 127;
      const unsigned short* gH = WH + (size_t)(bn + colL) * K + k0 + kc * 8;
      const unsigned short* gL = WL + (size_t)(bn + colL) * K + k0 + kc * 8;
      __builtin_amdgcn_global_load_lds(AS1C(gH), AS3(&BsH[(j * 256 + w * 64) * 8]), 16, 0, 0);
      __builtin_amdgcn_global_load_lds(AS1C(gL), AS3(&BsL[(j * 256 + w * 64) * 8]), 16, 0, 0);
    }

    // --- A split + LDS store ---
#pragma unroll
    for (int i = 0; i < 4; ++i) {
      int chunk = i * 256 + tid;
      int row = chunk >> 3;
      int kc4 = chunk & 7;
      unsigned short h0, h1, h2, h3, l0, l1, l2, l3;
      split_f32(av[i].x, h0, l0);
      split_f32(av[i].y, h1, l1);
      split_f32(av[i].z, h2, l2);
      split_f32(av[i].w, h3, l3);
      ushortx4 hv = {h0, h1, h2, h3};
      ushortx4 lv = {l0, l1, l2, l3};
      *(ushortx4*)&AsH[row * 40 + kc4 * 4] = hv;
      *(ushortx4*)&AsL[row * 40 + kc4 * 4] = lv;
    }

    __syncthreads();  // drains lds-writes + global_load_lds (vmcnt) before reads

    // --- MFMA compute ---
    bf16x8 aH[4], aL[4];
#pragma unroll
    for (int fi = 0; fi < 4; ++fi) {
      int row = wm * 64 + fi * 16 + l15;
      aH[fi] = *(const bf16x8*)&AsH[row * 40 + quad * 8];
      aL[fi] = *(const bf16x8*)&AsL[row * 40 + quad * 8];
    }
#pragma unroll
    for (int fj = 0; fj < 4; ++fj) {
      int colL = wn * 64 + fj * 16 + l15;
      int cidx = quad * 128 + colL;
      bf16x8 bh = *(const bf16x8*)&BsH[cidx * 8];
      bf16x8 bl = *(const bf16x8*)&BsL[cidx * 8];
#pragma unroll
      for (int fi = 0; fi < 4; ++fi) {
        floatx4 t = acc[fi][fj];
        t = __builtin_amdgcn_mfma_f32_16x16x32_bf16(aH[fi], bl, t, 0, 0, 0);
        t = __builtin_amdgcn_mfma_f32_16x16x32_bf16(aL[fi], bh, t, 0, 0, 0);
        t = __builtin_amdgcn_mfma_f32_16x16x32_bf16(aH[fi], bh, t, 0, 0, 0);
        acc[fi][fj] = t;
      }
    }
  }

  // --- epilogue: C/D layout col=lane&15, row=quad*4+reg ---
  float bcol[4];
#pragma unroll
  for (int fj = 0; fj < 4; ++fj)
    bcol[fj] = BIAS ? bias[bn + wn * 64 + fj * 16 + l15] : 0.f;

#pragma unroll
  for (int fi = 0; fi < 4; ++fi) {
    int rb = bm + wm * 64 + fi * 16 + quad * 4;
#pragma unroll
    for (int r = 0; r < 4; ++r) {
      int row = rb + r;
      if (row < M) {
        float* Cp = C + (size_t)row * HDIM + bn + wn * 64 + l15;
#pragma unroll
        for (int fj = 0; fj < 4; ++fj) {
          float v = acc[fi][fj][r] + bcol[fj];
          if (RELU) v = fmaxf(v, 0.f);
          Cp[fj * 16] = v;
        }
      }
    }
  }
}

// ---------------- GCN aggregation (pull via CSR), one wave per node ----------------

__global__ __launch_bounds__(256)
void aggregate_kernel(const float* __restrict__ t, const float* __restrict__ dinv,
                      const int* __restrict__ rowptr, const int* __restrict__ col,
                      const float* __restrict__ bias, float* __restrict__ outp, int n) {
  int gw = (int)((blockIdx.x * 256 + threadIdx.x) >> 6);
  int lane = threadIdx.x & 63;
  if (gw >= n) return;
  float di = dinv[gw];
  const float4* ti = (const float4*)(t + (size_t)gw * HDIM);
  float4 v = ti[lane];
  float ss = di * di;
  float ax = v.x * ss, ay = v.y * ss, az = v.z * ss, aw = v.w * ss;
  int e0 = rowptr[gw], e1 = rowptr[gw + 1];
  for (int e = e0; e < e1; ++e) {
    int s = col[e];
    float wgt = dinv[s] * di;
    const float4* ts = (const float4*)(t + (size_t)s * HDIM);
    float4 u = ts[lane];
    ax = fmaf(u.x, wgt, ax);
    ay = fmaf(u.y, wgt, ay);
    az = fmaf(u.z, wgt, az);
    aw = fmaf(u.w, wgt, aw);
  }
  const float4* b4 = (const float4*)bias;
  float4 bb = b4[lane];
  float4 r;
  r.x = fmaxf(ax + bb.x, 0.f);
  r.y = fmaxf(ay + bb.y, 0.f);
  r.z = fmaxf(az + bb.z, 0.f);
  r.w = fmaxf(aw + bb.w, 0.f);
  ((float4*)(outp + (size_t)gw * HDIM))[lane] = r;
}

// ---------------- row softmax, one wave per row ----------------

__global__ __launch_bounds__(256)
void softmax_kernel(const float* __restrict__ logits, float* __restrict__ outp, int n) {
  int gw = (int)((blockIdx.x * 256 + threadIdx.x) >> 6);
  int lane = threadIdx.x & 63;
  if (gw >= n) return;
  const float4* rp = (const float4*)(logits + (size_t)gw * HDIM);
  float4 v = rp[lane];
  float m = fmaxf(fmaxf(v.x, v.y), fmaxf(v.z, v.w));
#pragma unroll
  for (int off = 1; off < 64; off <<= 1) m = fmaxf(m, __shfl_xor(m, off));
  float ex = expf(v.x - m), ey = expf(v.y - m), ez = expf(v.z - m), ew = expf(v.w - m);
  float s = ex + ey + ez + ew;
#pragma unroll
  for (int off = 1; off < 64; off <<= 1) s += __shfl_xor(s, off);
  float inv = 1.0f / s;
  float4 r = make_float4(ex * inv, ey * inv, ez * inv, ew * inv);
  ((float4*)(outp + (size_t)gw * HDIM))[lane] = r;
}

// ---------------- launch ----------------

extern "C" void kernel_launch(void* const* d_in, const int* in_sizes, int n_in,
                              void* d_out, int out_size, void* d_ws, size_t ws_size,
                              hipStream_t stream) {
  const float* x   = (const float*)d_in[0];
  const int*   ei  = (const int*)d_in[1];
  const float* W1  = (const float*)d_in[2];
  const float* b1  = (const float*)d_in[3];
  const float* Wg1 = (const float*)d_in[4];
  const float* bg1 = (const float*)d_in[5];
  const float* Wg2 = (const float*)d_in[6];
  const float* bg2 = (const float*)d_in[7];
  const float* W2  = (const float*)d_in[8];
  const float* b2  = (const float*)d_in[9];
  const float* W3  = (const float*)d_in[10];
  const float* b3  = (const float*)d_in[11];
  float* out = (float*)d_out;

  const int K1 = in_sizes[2] / HDIM;  // 128
  const int N  = in_sizes[0] / K1;    // 50000
  const int E  = in_sizes[1] / 2;     // 300000

  char* w = (char*)d_ws;
  auto alloc = [&](size_t bytes) -> char* {
    char* p = w;
    w += (bytes + 255) & ~(size_t)255;
    return p;
  };
  float* bufA   = (float*)alloc((size_t)N * HDIM * sizeof(float));
  float* dinv   = (float*)alloc((size_t)N * sizeof(float));
  int*   deg    = (int*)alloc((size_t)N * sizeof(int));
  int*   rowptr = (int*)alloc((size_t)(N + 1) * sizeof(int));
  int*   cursor = (int*)alloc((size_t)N * sizeof(int));
  int*   col    = (int*)alloc((size_t)E * sizeof(int));
  const int nb  = (N + 255) / 256;
  int*   bsum   = (int*)alloc((size_t)nb * sizeof(int));
  int*   boff   = (int*)alloc((size_t)nb * sizeof(int));
  // split weights (transposed [256][K], hi/lo bf16)
  unsigned short* W1tH  = (unsigned short*)alloc((size_t)HDIM * K1 * 2);
  unsigned short* W1tL  = (unsigned short*)alloc((size_t)HDIM * K1 * 2);
  unsigned short* Wg1tH = (unsigned short*)alloc((size_t)HDIM * HDIM * 2);
  unsigned short* Wg1tL = (unsigned short*)alloc((size_t)HDIM * HDIM * 2);
  unsigned short* Wg2tH = (unsigned short*)alloc((size_t)HDIM * HDIM * 2);
  unsigned short* Wg2tL = (unsigned short*)alloc((size_t)HDIM * HDIM * 2);
  unsigned short* W2tH  = (unsigned short*)alloc((size_t)HDIM * HDIM * 2);
  unsigned short* W2tL  = (unsigned short*)alloc((size_t)HDIM * HDIM * 2);
  unsigned short* W3tH  = (unsigned short*)alloc((size_t)HDIM * HDIM * 2);
  unsigned short* W3tL  = (unsigned short*)alloc((size_t)HDIM * HDIM * 2);

  const int ge = (E + 255) / 256;
  const int gn = (N + 255) / 256;
  const int kshift1 = (K1 == 128) ? 7 : 8;

  // weight prep
  prep_w_kernel<<<(HDIM * K1 + 255) / 256, 256, 0, stream>>>(W1, W1tH, W1tL, kshift1);
  prep_w_kernel<<<(HDIM * HDIM + 255) / 256, 256, 0, stream>>>(Wg1, Wg1tH, Wg1tL, 8);
  prep_w_kernel<<<(HDIM * HDIM + 255) / 256, 256, 0, stream>>>(Wg2, Wg2tH, Wg2tL, 8);
  prep_w_kernel<<<(HDIM * HDIM + 255) / 256, 256, 0, stream>>>(W2, W2tH, W2tL, 8);
  prep_w_kernel<<<(HDIM * HDIM + 255) / 256, 256, 0, stream>>>(W3, W3tH, W3tL, 8);

  // CSR build + dinv
  hipMemsetAsync(deg, 0, (size_t)N * sizeof(int), stream);
  deg_count_kernel<<<ge, 256, 0, stream>>>(ei, deg, E);
  dinv_kernel<<<gn, 256, 0, stream>>>(deg, dinv, N);
  block_sum_kernel<<<nb, 256, 0, stream>>>(deg, bsum, N);
  scan_bsums_kernel<<<1, 256, 0, stream>>>(bsum, boff, rowptr, nb, N);
  scan_final_kernel<<<nb, 256, 0, stream>>>(deg, boff, rowptr, cursor, N);
  fill_csr_kernel<<<ge, 256, 0, stream>>>(ei, cursor, col, E);

  dim3 ggrid(HDIM / 128, (N + 127) / 128);
  const int gagg = (N + 3) / 4;

  // h0 = relu(x@W1+b1) -> bufA
  mfma_gemm_kernel<true, true><<<ggrid, 256, 0, stream>>>(x, W1tH, W1tL, b1, bufA, N, K1);
  // t1 = h0@Wg1 -> out
  mfma_gemm_kernel<false, false><<<ggrid, 256, 0, stream>>>(bufA, Wg1tH, Wg1tL, nullptr, out, N, HDIM);
  // h1 = relu(agg(t1)+bg1) -> bufA
  aggregate_kernel<<<gagg, 256, 0, stream>>>(out, dinv, rowptr, col, bg1, bufA, N);
  // t2 = h1@Wg2 -> out
  mfma_gemm_kernel<false, false><<<ggrid, 256, 0, stream>>>(bufA, Wg2tH, Wg2tL, nullptr, out, N, HDIM);
  // h2 = relu(agg(t2)+bg2) -> bufA
  aggregate_kernel<<<gagg, 256, 0, stream>>>(out, dinv, rowptr, col, bg2, bufA, N);
  // h3 = relu(h2@W2+b2) -> out
  mfma_gemm_kernel<true, true><<<ggrid, 256, 0, stream>>>(bufA, W2tH, W2tL, b2, out, N, HDIM);
  // logits = h3@W3+b3 -> bufA
  mfma_gemm_kernel<true, false><<<ggrid, 256, 0, stream>>>(out, W3tH, W3tL, b3, bufA, N, HDIM);
  // out = softmax(logits)
  softmax_kernel<<<gagg, 256, 0, stream>>>(bufA, out, N);
}